// Round 4
// baseline (326.965 us; speedup 1.0000x reference)
//
#include <hip/hip_runtime.h>
#include <stdint.h>

#define BHALF 4096
#define NROWS 8192
#define DDIM  512
#define KNEG  8190.0f

#define BM 128
#define BN 128
#define BK 32
#define LDSS 40   // LDS row stride in bf16 elems (32 + 8 pad = 80 B)

typedef short v8s __attribute__((ext_vector_type(8)));   // 8 bf16 for MFMA A/B
typedef float v4f __attribute__((ext_vector_type(4)));   // MFMA C/D

static __device__ inline float bf2f(uint32_t u) {
    union { uint32_t i; float f; } c; c.i = u << 16; return c.f;
}
static __device__ inline uint32_t f2bf(float f) {
    union { float f; uint32_t i; } c; c.f = f;
    return (c.i + 0x7fffu + ((c.i >> 16) & 1u)) >> 16;   // RNE, low 16 bits valid
}

// -------- Kernel S: sentinel. If the final result errs by ~4.0 vs ref 9.0,
// this ran but the rest of the pipeline did not. Overwritten by finalize.
__global__ void sentinel_kernel(float* __restrict__ out) { out[0] = 5.0f; }

// -------- Kernel 0: input dtype probe (bf16 vs fp32), 1 block x 64 threads --------
// bf16 data: low half-word of each 32b word is a ~N(0,1) bf16 -> exponent ~[110,129].
// fp32 data: those bits are random mantissa bits -> uniform exponent field.
__global__ void dtype_probe(const uint32_t* __restrict__ w1, int* __restrict__ flag)
{
    int tid = threadIdx.x;
    uint32_t w = w1[tid * 977 + 13];       // stays < 64K words: in-bounds either way
    uint32_t e = (w >> 7) & 0xFFu;
    int bad = (e < 100u || e > 140u) ? 1 : 0;
    for (int m = 32; m; m >>= 1) bad += __shfl_xor(bad, m);
    if (tid == 0) flag[0] = (bad > 16) ? 1 : 0;   // 1 => inputs are float32
}

// -------- Kernel 1: per-row inverse L2 norm + zero accumulators --------
__global__ __launch_bounds__(256) void rownorm_kernel(
    const void* __restrict__ o1, const void* __restrict__ o2,
    const int* __restrict__ flag,
    float* __restrict__ rn, float* __restrict__ den, float* __restrict__ num)
{
    int row = blockIdx.x, tid = threadIdx.x;
    float f0, f1;
    if (flag[0] == 0) {
        const uint16_t* s = (row < BHALF)
            ? (const uint16_t*)o1 + (size_t)row * DDIM
            : (const uint16_t*)o2 + (size_t)(row - BHALF) * DDIM;
        uint32_t u = ((const uint32_t*)s)[tid];     // 2 bf16 per thread
        f0 = bf2f(u & 0xffffu); f1 = bf2f(u >> 16);
    } else {
        const float* s = (row < BHALF)
            ? (const float*)o1 + (size_t)row * DDIM
            : (const float*)o2 + (size_t)(row - BHALF) * DDIM;
        f0 = s[2 * tid]; f1 = s[2 * tid + 1];
    }
    float ss = f0 * f0 + f1 * f1;
    for (int m = 32; m; m >>= 1) ss += __shfl_xor(ss, m);
    __shared__ float wsum[4];
    if ((tid & 63) == 0) wsum[tid >> 6] = ss;
    __syncthreads();
    if (tid == 0) {
        float tot = wsum[0] + wsum[1] + wsum[2] + wsum[3];
        rn[row]  = rsqrtf(tot);
        den[row] = 0.f;
        num[row] = 0.f;
    }
}

// -------- Kernel 2: Gram matrix on RAW rows, normalize in epilogue, fused exp sums ----
// Grid (64,64), 256 threads (4 waves). 128x128 tile, BK=32, 16x16x32 bf16 MFMA.
// C/D layout: col = lane&15, row = (lane>>4)*4 + reg.
__global__ __launch_bounds__(256) void SupCon_hcl_49323404427556_kernel(
    const void* __restrict__ o1, const void* __restrict__ o2,
    const int* __restrict__ flag, const float* __restrict__ rn,
    float* __restrict__ den, float* __restrict__ num, float* __restrict__ cpos)
{
    __shared__ alignas(16) uint16_t la[BM * LDSS];
    __shared__ alignas(16) uint16_t lb[BN * LDSS];
    __shared__ float rnA[BM];
    __shared__ float rnB[BN];

    int tid  = threadIdx.x;
    int wave = tid >> 6, lane = tid & 63;
    int quad = lane >> 4, l16 = lane & 15;
    int i0 = blockIdx.y * BM, j0 = blockIdx.x * BN;
    int wrow = (wave >> 1) * 64, wcol = (wave & 1) * 64;

    if (tid < BM) rnA[tid] = rn[i0 + tid];
    else          rnB[tid - BM] = rn[j0 + (tid - BM)];

    // A/B tile base pointers (each 128-row tile lies entirely in o1 or o2)
    const uint16_t *A16, *B16;
    const float    *A32, *B32;
    if (i0 < BHALF) { A16 = (const uint16_t*)o1 + (size_t)i0 * DDIM;
                      A32 = (const float*)o1    + (size_t)i0 * DDIM; }
    else            { A16 = (const uint16_t*)o2 + (size_t)(i0 - BHALF) * DDIM;
                      A32 = (const float*)o2    + (size_t)(i0 - BHALF) * DDIM; }
    if (j0 < BHALF) { B16 = (const uint16_t*)o1 + (size_t)j0 * DDIM;
                      B32 = (const float*)o1    + (size_t)j0 * DDIM; }
    else            { B16 = (const uint16_t*)o2 + (size_t)(j0 - BHALF) * DDIM;
                      B32 = (const float*)o2    + (size_t)(j0 - BHALF) * DDIM; }

    int isF32 = flag[0];

    v4f acc[4][4];
    v4f z = {0.f, 0.f, 0.f, 0.f};
    #pragma unroll
    for (int a = 0; a < 4; ++a)
        #pragma unroll
        for (int b = 0; b < 4; ++b) acc[a][b] = z;

    int srow = tid >> 2;          // 0..63 (+64 second pass)
    int sc   = (tid & 3) * 8;     // k-offset in elems, 16B chunks

    for (int kb = 0; kb < DDIM / BK; ++kb) {
        int kbase = kb * BK;
        __syncthreads();
        if (!isF32) {
            #pragma unroll
            for (int p = 0; p < 2; ++p) {
                int r = srow + p * 64;
                *(uint4*)(&la[r * LDSS + sc]) = *(const uint4*)(A16 + (size_t)r * DDIM + kbase + sc);
                *(uint4*)(&lb[r * LDSS + sc]) = *(const uint4*)(B16 + (size_t)r * DDIM + kbase + sc);
            }
        } else {
            #pragma unroll
            for (int p = 0; p < 2; ++p) {
                int r = srow + p * 64;
                const float* pa = A32 + (size_t)r * DDIM + kbase + sc;
                const float* pb = B32 + (size_t)r * DDIM + kbase + sc;
                uint4 wa, wb;
                wa.x = f2bf(pa[0]) | (f2bf(pa[1]) << 16);
                wa.y = f2bf(pa[2]) | (f2bf(pa[3]) << 16);
                wa.z = f2bf(pa[4]) | (f2bf(pa[5]) << 16);
                wa.w = f2bf(pa[6]) | (f2bf(pa[7]) << 16);
                wb.x = f2bf(pb[0]) | (f2bf(pb[1]) << 16);
                wb.y = f2bf(pb[2]) | (f2bf(pb[3]) << 16);
                wb.z = f2bf(pb[4]) | (f2bf(pb[5]) << 16);
                wb.w = f2bf(pb[6]) | (f2bf(pb[7]) << 16);
                *(uint4*)(&la[r * LDSS + sc]) = wa;
                *(uint4*)(&lb[r * LDSS + sc]) = wb;
            }
        }
        __syncthreads();

        v8s af[4], bfr[4];
        #pragma unroll
        for (int t = 0; t < 4; ++t) {
            af[t]  = *(const v8s*)(&la[(wrow + 16 * t + l16) * LDSS + quad * 8]);
            bfr[t] = *(const v8s*)(&lb[(wcol + 16 * t + l16) * LDSS + quad * 8]);
        }
        #pragma unroll
        for (int mt = 0; mt < 4; ++mt)
            #pragma unroll
            for (int nt = 0; nt < 4; ++nt)
                acc[mt][nt] = __builtin_amdgcn_mfma_f32_16x16x32_bf16(
                    af[mt], bfr[nt], acc[mt][nt], 0, 0, 0);
    }

    // Epilogue: d = acc * rn_i * rn_j; e = exp(d); den += e, num += e^3 over negatives;
    // partner element (j == i^4096) stores cpos = e^2 (exactly one writer grid-wide).
    #pragma unroll
    for (int mt = 0; mt < 4; ++mt) {
        #pragma unroll
        for (int r = 0; r < 4; ++r) {
            int li = wrow + 16 * mt + quad * 4 + r;
            int gi = i0 + li;
            int partner = gi ^ BHALF;
            float ri = rnA[li];
            float pd = 0.f, pn = 0.f;
            #pragma unroll
            for (int nt = 0; nt < 4; ++nt) {
                int lj = wcol + 16 * nt + l16;
                int gj = j0 + lj;
                float d = acc[mt][nt][r] * ri * rnB[lj];
                float e = __expf(d);
                if (gj == partner) cpos[gi] = e * e;
                if (gj != gi && gj != partner) { pd += e; pn += e * e * e; }
            }
            for (int m = 1; m < 16; m <<= 1) {
                pd += __shfl_xor(pd, m);
                pn += __shfl_xor(pn, m);
            }
            if (l16 == 0) {
                atomicAdd(&den[gi], pd);
                atomicAdd(&num[gi], pn);
            }
        }
    }
}

// -------- Kernel 3: final loss reduction (fp32 OUTPUT — reference returns float32) ----
__global__ __launch_bounds__(256) void finalize_kernel(
    const float* __restrict__ den, const float* __restrict__ num,
    const float* __restrict__ cpos, float* __restrict__ out)
{
    int tid = threadIdx.x;
    float s = 0.f;
    for (int i = tid; i < NROWS; i += 256) {
        float sc = num[i] / den[i];                 // neg_exp_sum
        s += logf(1.0f + KNEG * sc / cpos[i]);      // -log(ratio)
    }
    for (int m = 32; m; m >>= 1) s += __shfl_xor(s, m);
    __shared__ float wsum[4];
    if ((tid & 63) == 0) wsum[tid >> 6] = s;
    __syncthreads();
    if (tid == 0) {
        float tot = wsum[0] + wsum[1] + wsum[2] + wsum[3];
        out[0] = tot / (float)NROWS;                // fp32 store, full 4 bytes
    }
}

extern "C" void kernel_launch(void* const* d_in, const int* in_sizes, int n_in,
                              void* d_out, int out_size, void* d_ws, size_t ws_size,
                              hipStream_t stream)
{
    // inputs in setup_inputs() order: [0]=features (unused), [1]=out_1, [2]=out_2, [3]=indexes
    const void* o1 = d_in[1];
    const void* o2 = d_in[2];

    // workspace: 4 x 8192 floats + flag = 128 KB + 4 B
    float* rn   = (float*)d_ws;
    float* den  = rn + NROWS;
    float* num  = den + NROWS;
    float* cpos = num + NROWS;
    int*   flag = (int*)(cpos + NROWS);

    sentinel_kernel<<<1, 1, 0, stream>>>((float*)d_out);
    dtype_probe<<<1, 64, 0, stream>>>((const uint32_t*)o1, flag);
    rownorm_kernel<<<NROWS, 256, 0, stream>>>(o1, o2, flag, rn, den, num);
    dim3 grid(NROWS / BN, NROWS / BM);
    SupCon_hcl_49323404427556_kernel<<<grid, 256, 0, stream>>>(o1, o2, flag, rn, den, num, cpos);
    finalize_kernel<<<1, 256, 0, stream>>>(den, num, cpos, (float*)d_out);
}

// Round 5
// 282.322 us; speedup vs baseline: 1.1581x; 1.1581x over previous
//
#include <hip/hip_runtime.h>
#include <stdint.h>

#define BHALF 4096
#define NROWS 8192
#define DDIM  512
#define KNEG  8190.0f

#define BM   128
#define BK   32
#define NTIL 64                        // 8192 / 128
#define TBLK (NTIL * (NTIL + 1) / 2)   // 2080 upper-triangle tiles

typedef short v8s __attribute__((ext_vector_type(8)));   // 8 bf16 MFMA A/B frag
typedef float v4f __attribute__((ext_vector_type(4)));   // MFMA C/D frag

static __device__ inline float bf2f(uint32_t u) {
    union { uint32_t i; float f; } c; c.i = u << 16; return c.f;
}
static __device__ inline uint32_t f2bf(float f) {
    union { float f; uint32_t i; } c; c.f = f;
    return (c.i + 0x7fffu + ((c.i >> 16) & 1u)) >> 16;
}

// async global->LDS, 16 B per lane; LDS dest = wave-uniform base + lane*16
#define GLL16(gp, lp)                                                         \
    __builtin_amdgcn_global_load_lds(                                         \
        (__attribute__((address_space(1))) void*)(gp),                        \
        (__attribute__((address_space(3))) void*)(lp), 16, 0, 0)

// -------- Kernel 0: input dtype probe (bf16 vs fp32) --------
__global__ void dtype_probe(const uint32_t* __restrict__ w1, int* __restrict__ flag)
{
    int tid = threadIdx.x;
    uint32_t w = w1[tid * 977 + 13];
    uint32_t e = (w >> 7) & 0xFFu;
    int bad = (e < 100u || e > 140u) ? 1 : 0;
    for (int m = 32; m; m >>= 1) bad += __shfl_xor(bad, m);
    if (tid == 0) flag[0] = (bad > 16) ? 1 : 0;   // 1 => float32 inputs
}

// -------- Kernel 1: per-row inverse L2 norm + zero accumulators --------
__global__ __launch_bounds__(256) void rownorm_kernel(
    const void* __restrict__ o1, const void* __restrict__ o2,
    const int* __restrict__ flag,
    float* __restrict__ rn, float* __restrict__ den, float* __restrict__ num)
{
    int row = blockIdx.x, tid = threadIdx.x;
    float f0, f1;
    if (flag[0] == 0) {
        const uint16_t* s = (row < BHALF)
            ? (const uint16_t*)o1 + (size_t)row * DDIM
            : (const uint16_t*)o2 + (size_t)(row - BHALF) * DDIM;
        uint32_t u = ((const uint32_t*)s)[tid];
        f0 = bf2f(u & 0xffffu); f1 = bf2f(u >> 16);
    } else {
        const float* s = (row < BHALF)
            ? (const float*)o1 + (size_t)row * DDIM
            : (const float*)o2 + (size_t)(row - BHALF) * DDIM;
        f0 = s[2 * tid]; f1 = s[2 * tid + 1];
    }
    float ss = f0 * f0 + f1 * f1;
    for (int m = 32; m; m >>= 1) ss += __shfl_xor(ss, m);
    __shared__ float wsum[4];
    if ((tid & 63) == 0) wsum[tid >> 6] = ss;
    __syncthreads();
    if (tid == 0) {
        rn[row]  = rsqrtf(wsum[0] + wsum[1] + wsum[2] + wsum[3]);
        den[row] = 0.f;
        num[row] = 0.f;
    }
}

// -------- Kernel 2: upper-triangle Gram tiles + fused exp row/col sums --------
// 1D grid of 2080 tiles, 256 threads (4 waves), 128x128 tile, BK=32.
// LDS layout: [row][slot] 64 B rows, slot = (chunk + (row>>1)) & 3  (XOR/rotate
// swizzle -> ds_read_b128 is 2-way/free; global_load_lds lane order preserved).
// C/D layout: col = lane&15, row = quad*4 + reg.
__global__ __launch_bounds__(256) void SupCon_hcl_49323404427556_kernel(
    const void* __restrict__ o1, const void* __restrict__ o2,
    const int* __restrict__ flag, const float* __restrict__ rn,
    float* __restrict__ den, float* __restrict__ num, float* __restrict__ cpos)
{
    __shared__ alignas(16) uint16_t la[BM * BK];   // 8 KiB
    __shared__ alignas(16) uint16_t lb[BM * BK];   // 8 KiB
    __shared__ float rnA[BM], rnB[BM];

    int tid  = threadIdx.x;
    int wave = tid >> 6, lane = tid & 63;
    int quad = lane >> 4, l16 = lane & 15;
    int wrow = (wave >> 1) * 64, wcol = (wave & 1) * 64;

    // ---- triangular decode: t -> (bi, bj), bj >= bi ----
    int t = blockIdx.x;
    int bi = (int)(64.5f - sqrtf(64.5f * 64.5f - 2.0f * (float)t));
    while (bi > 0 && (64 * bi - (bi * (bi - 1)) / 2) > t) --bi;
    while ((64 * (bi + 1) - ((bi + 1) * bi) / 2) <= t) ++bi;
    int bj = bi + (t - (64 * bi - (bi * (bi - 1)) / 2));
    int i0 = bi * BM, j0 = bj * BM;
    bool diag = (bi == bj);

    if (tid < BM) rnA[tid] = rn[i0 + tid];
    else          rnB[tid - BM] = rn[j0 + (tid - BM)];

    const uint16_t *A16, *B16; const float *A32, *B32;
    if (i0 < BHALF) { A16 = (const uint16_t*)o1 + (size_t)i0 * DDIM;
                      A32 = (const float*)o1    + (size_t)i0 * DDIM; }
    else            { A16 = (const uint16_t*)o2 + (size_t)(i0 - BHALF) * DDIM;
                      A32 = (const float*)o2    + (size_t)(i0 - BHALF) * DDIM; }
    if (j0 < BHALF) { B16 = (const uint16_t*)o1 + (size_t)j0 * DDIM;
                      B32 = (const float*)o1    + (size_t)j0 * DDIM; }
    else            { B16 = (const uint16_t*)o2 + (size_t)(j0 - BHALF) * DDIM;
                      B32 = (const float*)o2    + (size_t)(j0 - BHALF) * DDIM; }
    int isF32 = flag[0];

    v4f acc[4][4];
    v4f z = {0.f, 0.f, 0.f, 0.f};
    #pragma unroll
    for (int a = 0; a < 4; ++a)
        #pragma unroll
        for (int b = 0; b < 4; ++b) acc[a][b] = z;

    // ---- staging geometry: wave w stages rows [32w,32w+32) of A and B ----
    int rloc = lane >> 2;                 // 0..15
    int slot = lane & 3;                  // LDS 16B slot within row
    int rA   = 32 * wave + rloc;          // base row (instr 0); instr 1 = +16
    int chk  = (slot - (rA >> 1)) & 3;    // global chunk this lane fetches (same for +16)
    const uint16_t* gA = A16 + (size_t)rA * DDIM + chk * 8;
    const uint16_t* gB = B16 + (size_t)rA * DDIM + chk * 8;
    uint16_t* sA0 = &la[(32 * wave) * BK];
    uint16_t* sA1 = &la[(32 * wave + 16) * BK];
    uint16_t* sB0 = &lb[(32 * wave) * BK];
    uint16_t* sB1 = &lb[(32 * wave + 16) * BK];

    const uint16_t* lbp = diag ? la : lb;
    int sfrag = (quad + (l16 >> 1)) & 3;  // read-side swizzled slot

    for (int kb = 0; kb < DDIM / BK; ++kb) {
        __syncthreads();                  // prior iter's LDS reads done
        if (!isF32) {
            GLL16(gA + kb * BK, sA0);
            GLL16(gA + kb * BK + 16 * DDIM, sA1);
            if (!diag) {
                GLL16(gB + kb * BK, sB0);
                GLL16(gB + kb * BK + 16 * DDIM, sB1);
            }
        } else {
            #pragma unroll
            for (int p = 0; p < 2; ++p) {
                int r = rA + p * 16;
                const float* pa = A32 + (size_t)r * DDIM + kb * BK + chk * 8;
                uint4 wa;
                wa.x = f2bf(pa[0]) | (f2bf(pa[1]) << 16);
                wa.y = f2bf(pa[2]) | (f2bf(pa[3]) << 16);
                wa.z = f2bf(pa[4]) | (f2bf(pa[5]) << 16);
                wa.w = f2bf(pa[6]) | (f2bf(pa[7]) << 16);
                *(uint4*)(&la[r * BK + slot * 8]) = wa;
                if (!diag) {
                    const float* pb = B32 + (size_t)r * DDIM + kb * BK + chk * 8;
                    uint4 wb;
                    wb.x = f2bf(pb[0]) | (f2bf(pb[1]) << 16);
                    wb.y = f2bf(pb[2]) | (f2bf(pb[3]) << 16);
                    wb.z = f2bf(pb[4]) | (f2bf(pb[5]) << 16);
                    wb.w = f2bf(pb[6]) | (f2bf(pb[7]) << 16);
                    *(uint4*)(&lb[r * BK + slot * 8]) = wb;
                }
            }
        }
        __syncthreads();                  // drains vmcnt/lgkm, publishes LDS

        v8s af[4], bfr[4];
        #pragma unroll
        for (int tt = 0; tt < 4; ++tt) {
            af[tt]  = *(const v8s*)(&la [(wrow + 16 * tt + l16) * BK + sfrag * 8]);
            bfr[tt] = *(const v8s*)(&lbp[(wcol + 16 * tt + l16) * BK + sfrag * 8]);
        }
        #pragma unroll
        for (int mt = 0; mt < 4; ++mt)
            #pragma unroll
            for (int nt = 0; nt < 4; ++nt)
                acc[mt][nt] = __builtin_amdgcn_mfma_f32_16x16x32_bf16(
                    af[mt], bfr[nt], acc[mt][nt], 0, 0, 0);
    }

    // ---- epilogue: in-place e = exp(d * rn_i * rn_j) ----
    #pragma unroll
    for (int mt = 0; mt < 4; ++mt) {
        #pragma unroll
        for (int nt = 0; nt < 4; ++nt) {
            float rj = rnB[wcol + 16 * nt + l16];
            #pragma unroll
            for (int r = 0; r < 4; ++r) {
                float ri = rnA[wrow + 16 * mt + quad * 4 + r];
                acc[mt][nt][r] = __expf(acc[mt][nt][r] * ri * rj);
            }
        }
    }

    // ---- row pass: den[gi] += e, num[gi] += e^3 over negatives; partner -> cpos[gi] ----
    #pragma unroll
    for (int mt = 0; mt < 4; ++mt) {
        #pragma unroll
        for (int r = 0; r < 4; ++r) {
            int gi = i0 + wrow + 16 * mt + quad * 4 + r;
            int partner = gi ^ BHALF;
            float pd = 0.f, pn = 0.f;
            #pragma unroll
            for (int nt = 0; nt < 4; ++nt) {
                int gj = j0 + wcol + 16 * nt + l16;
                float e = acc[mt][nt][r];
                if (gj == partner) cpos[gi] = e * e;
                if (gj != gi && gj != partner) { pd += e; pn += e * e * e; }
            }
            #pragma unroll
            for (int m = 1; m < 16; m <<= 1) {
                pd += __shfl_xor(pd, m);
                pn += __shfl_xor(pn, m);
            }
            if (l16 == 0) {
                atomicAdd(&den[gi], pd);
                atomicAdd(&num[gi], pn);
            }
        }
    }

    // ---- col pass (off-diagonal only): transposed contribution ----
    if (!diag) {
        #pragma unroll
        for (int nt = 0; nt < 4; ++nt) {
            int gj = j0 + wcol + 16 * nt + l16;
            int pj = gj ^ BHALF;
            float cd = 0.f, cn = 0.f;
            #pragma unroll
            for (int mt = 0; mt < 4; ++mt) {
                #pragma unroll
                for (int r = 0; r < 4; ++r) {
                    int gi = i0 + wrow + 16 * mt + quad * 4 + r;
                    float e = acc[mt][nt][r];
                    if (gi == pj) cpos[gj] = e * e;
                    else { cd += e; cn += e * e * e; }
                }
            }
            cd += __shfl_xor(cd, 16); cn += __shfl_xor(cn, 16);
            cd += __shfl_xor(cd, 32); cn += __shfl_xor(cn, 32);
            if (quad == 0) {
                atomicAdd(&den[gj], cd);
                atomicAdd(&num[gj], cn);
            }
        }
    }
}

// -------- Kernel 3: final loss reduction (fp32 output) --------
__global__ __launch_bounds__(256) void finalize_kernel(
    const float* __restrict__ den, const float* __restrict__ num,
    const float* __restrict__ cpos, float* __restrict__ out)
{
    int tid = threadIdx.x;
    float s = 0.f;
    for (int i = tid; i < NROWS; i += 256) {
        float sc = num[i] / den[i];
        s += logf(1.0f + KNEG * sc / cpos[i]);
    }
    for (int m = 32; m; m >>= 1) s += __shfl_xor(s, m);
    __shared__ float wsum[4];
    if ((tid & 63) == 0) wsum[tid >> 6] = s;
    __syncthreads();
    if (tid == 0)
        out[0] = (wsum[0] + wsum[1] + wsum[2] + wsum[3]) / (float)NROWS;
}

extern "C" void kernel_launch(void* const* d_in, const int* in_sizes, int n_in,
                              void* d_out, int out_size, void* d_ws, size_t ws_size,
                              hipStream_t stream)
{
    const void* o1 = d_in[1];
    const void* o2 = d_in[2];

    float* rn   = (float*)d_ws;
    float* den  = rn + NROWS;
    float* num  = den + NROWS;
    float* cpos = num + NROWS;
    int*   flag = (int*)(cpos + NROWS);

    dtype_probe<<<1, 64, 0, stream>>>((const uint32_t*)o1, flag);
    rownorm_kernel<<<NROWS, 256, 0, stream>>>(o1, o2, flag, rn, den, num);
    SupCon_hcl_49323404427556_kernel<<<TBLK, 256, 0, stream>>>(o1, o2, flag, rn, den, num, cpos);
    finalize_kernel<<<1, 256, 0, stream>>>(den, num, cpos, (float*)d_out);
}

// Round 6
// 192.661 us; speedup vs baseline: 1.6971x; 1.4654x over previous
//
#include <hip/hip_runtime.h>
#include <stdint.h>

#define BHALF 4096
#define NROWS 8192
#define DDIM  512
#define KNEG  8190.0f

#define BM   128
#define BK   32
#define NTIL 64                        // 8192 / 128
#define TBLK (NTIL * (NTIL + 1) / 2)   // 2080 upper-triangle tiles
#define RBLK 32                        // finalize stage-A blocks

typedef short v8s __attribute__((ext_vector_type(8)));   // 8 bf16 MFMA A/B frag
typedef float v4f __attribute__((ext_vector_type(4)));   // MFMA C/D frag

static __device__ inline float bf2f(uint32_t u) {
    union { uint32_t i; float f; } c; c.i = u << 16; return c.f;
}
static __device__ inline uint32_t f2bf(float f) {
    union { float f; uint32_t i; } c; c.f = f;
    return (c.i + 0x7fffu + ((c.i >> 16) & 1u)) >> 16;
}

// async global->LDS, 16 B per lane; LDS dest = wave-uniform base + lane*16
#define GLL16(gp, lp)                                                         \
    __builtin_amdgcn_global_load_lds(                                         \
        (__attribute__((address_space(1))) void*)(gp),                        \
        (__attribute__((address_space(3))) void*)(lp), 16, 0, 0)

// -------- Kernel 0: input dtype probe (bf16 vs fp32) --------
__global__ void dtype_probe(const uint32_t* __restrict__ w1, int* __restrict__ flag)
{
    int tid = threadIdx.x;
    uint32_t w = w1[tid * 977 + 13];
    uint32_t e = (w >> 7) & 0xFFu;
    int bad = (e < 100u || e > 140u) ? 1 : 0;
    for (int m = 32; m; m >>= 1) bad += __shfl_xor(bad, m);
    if (tid == 0) flag[0] = (bad > 16) ? 1 : 0;   // 1 => float32 inputs
}

// -------- Kernel 1: per-row inverse L2 norm (wave per row, no barriers) --------
__global__ __launch_bounds__(256) void rownorm_kernel(
    const void* __restrict__ o1, const void* __restrict__ o2,
    const int* __restrict__ flag, float* __restrict__ rn)
{
    int wave = threadIdx.x >> 6, lane = threadIdx.x & 63;
    int row = blockIdx.x * 4 + wave;
    float ss;
    if (flag[0] == 0) {
        const uint16_t* s = (row < BHALF)
            ? (const uint16_t*)o1 + (size_t)row * DDIM
            : (const uint16_t*)o2 + (size_t)(row - BHALF) * DDIM;
        uint4 v = ((const uint4*)s)[lane];          // 8 bf16
        float a0 = bf2f(v.x & 0xffffu), a1 = bf2f(v.x >> 16);
        float a2 = bf2f(v.y & 0xffffu), a3 = bf2f(v.y >> 16);
        float a4 = bf2f(v.z & 0xffffu), a5 = bf2f(v.z >> 16);
        float a6 = bf2f(v.w & 0xffffu), a7 = bf2f(v.w >> 16);
        ss = a0*a0 + a1*a1 + a2*a2 + a3*a3 + a4*a4 + a5*a5 + a6*a6 + a7*a7;
    } else {
        const float* s = (row < BHALF)
            ? (const float*)o1 + (size_t)row * DDIM
            : (const float*)o2 + (size_t)(row - BHALF) * DDIM;
        float4 a = ((const float4*)s)[2 * lane];
        float4 b = ((const float4*)s)[2 * lane + 1];
        ss = a.x*a.x + a.y*a.y + a.z*a.z + a.w*a.w
           + b.x*b.x + b.y*b.y + b.z*b.z + b.w*b.w;
    }
    for (int m = 32; m; m >>= 1) ss += __shfl_xor(ss, m);
    if (lane == 0) rn[row] = rsqrtf(ss);
}

// -------- Kernel 2: upper-triangle Gram tiles + fused exp sums, NO atomics --------
// 2080 tiles, 256 threads. Row-pass partials -> part[bj][gi]; col-pass -> part[bi][gj].
// Exactly one writer per slot, all slots written => no init, no atomics.
__global__ __launch_bounds__(256, 4) void SupCon_hcl_49323404427556_kernel(
    const void* __restrict__ o1, const void* __restrict__ o2,
    const int* __restrict__ flag, const float* __restrict__ rn,
    float* __restrict__ pden, float* __restrict__ pnum, float* __restrict__ cpos)
{
    __shared__ alignas(16) uint16_t la[BM * BK];   // 8 KiB
    __shared__ alignas(16) uint16_t lb[BM * BK];   // 8 KiB
    __shared__ float rnA[BM], rnB[BM];
    __shared__ float s_dr[BM][2], s_nr[BM][2], s_dc[BM][2], s_nc[BM][2];  // 4 KiB

    int tid  = threadIdx.x;
    int wave = tid >> 6, lane = tid & 63;
    int quad = lane >> 4, l16 = lane & 15;
    int wrow = (wave >> 1) * 64, wcol = (wave & 1) * 64;

    // ---- triangular decode: t -> (bi, bj), bj >= bi ----
    int t = blockIdx.x;
    int bi = (int)(64.5f - sqrtf(64.5f * 64.5f - 2.0f * (float)t));
    while (bi > 0 && (64 * bi - (bi * (bi - 1)) / 2) > t) --bi;
    while ((64 * (bi + 1) - ((bi + 1) * bi) / 2) <= t) ++bi;
    int bj = bi + (t - (64 * bi - (bi * (bi - 1)) / 2));
    int i0 = bi * BM, j0 = bj * BM;
    bool diag = (bi == bj);

    if (tid < BM) rnA[tid] = rn[i0 + tid];
    else          rnB[tid - BM] = rn[j0 + (tid - BM)];

    const uint16_t *A16, *B16; const float *A32, *B32;
    if (i0 < BHALF) { A16 = (const uint16_t*)o1 + (size_t)i0 * DDIM;
                      A32 = (const float*)o1    + (size_t)i0 * DDIM; }
    else            { A16 = (const uint16_t*)o2 + (size_t)(i0 - BHALF) * DDIM;
                      A32 = (const float*)o2    + (size_t)(i0 - BHALF) * DDIM; }
    if (j0 < BHALF) { B16 = (const uint16_t*)o1 + (size_t)j0 * DDIM;
                      B32 = (const float*)o1    + (size_t)j0 * DDIM; }
    else            { B16 = (const uint16_t*)o2 + (size_t)(j0 - BHALF) * DDIM;
                      B32 = (const float*)o2    + (size_t)(j0 - BHALF) * DDIM; }
    int isF32 = flag[0];

    v4f acc[4][4];
    v4f z = {0.f, 0.f, 0.f, 0.f};
    #pragma unroll
    for (int a = 0; a < 4; ++a)
        #pragma unroll
        for (int b = 0; b < 4; ++b) acc[a][b] = z;

    // ---- staging geometry: wave w stages rows [32w,32w+32) ----
    int rloc = lane >> 2;                 // 0..15
    int slot = lane & 3;                  // LDS 16B slot within 64B row
    int rA   = 32 * wave + rloc;          // base row; +16 for 2nd instr
    int chk  = (slot - (rA >> 1)) & 3;    // swizzled source chunk (same for +16)
    const uint16_t* gA = A16 + (size_t)rA * DDIM + chk * 8;
    const uint16_t* gB = B16 + (size_t)rA * DDIM + chk * 8;
    uint16_t* sA0 = &la[(32 * wave) * BK];
    uint16_t* sA1 = &la[(32 * wave + 16) * BK];
    uint16_t* sB0 = &lb[(32 * wave) * BK];
    uint16_t* sB1 = &lb[(32 * wave + 16) * BK];

    const uint16_t* lbp = diag ? la : lb;
    int sfrag = (quad + (l16 >> 1)) & 3;  // read-side swizzled slot

    for (int kb = 0; kb < DDIM / BK; ++kb) {
        __syncthreads();
        if (!isF32) {
            GLL16(gA + kb * BK, sA0);
            GLL16(gA + kb * BK + 16 * DDIM, sA1);
            if (!diag) {
                GLL16(gB + kb * BK, sB0);
                GLL16(gB + kb * BK + 16 * DDIM, sB1);
            }
        } else {
            #pragma unroll
            for (int p = 0; p < 2; ++p) {
                int r = rA + p * 16;
                const float* pa = A32 + (size_t)r * DDIM + kb * BK + chk * 8;
                uint4 wa;
                wa.x = f2bf(pa[0]) | (f2bf(pa[1]) << 16);
                wa.y = f2bf(pa[2]) | (f2bf(pa[3]) << 16);
                wa.z = f2bf(pa[4]) | (f2bf(pa[5]) << 16);
                wa.w = f2bf(pa[6]) | (f2bf(pa[7]) << 16);
                *(uint4*)(&la[r * BK + slot * 8]) = wa;
                if (!diag) {
                    const float* pb = B32 + (size_t)r * DDIM + kb * BK + chk * 8;
                    uint4 wb;
                    wb.x = f2bf(pb[0]) | (f2bf(pb[1]) << 16);
                    wb.y = f2bf(pb[2]) | (f2bf(pb[3]) << 16);
                    wb.z = f2bf(pb[4]) | (f2bf(pb[5]) << 16);
                    wb.w = f2bf(pb[6]) | (f2bf(pb[7]) << 16);
                    *(uint4*)(&lb[r * BK + slot * 8]) = wb;
                }
            }
        }
        __syncthreads();

        v8s af[4], bfr[4];
        #pragma unroll
        for (int tt = 0; tt < 4; ++tt) {
            af[tt]  = *(const v8s*)(&la [(wrow + 16 * tt + l16) * BK + sfrag * 8]);
            bfr[tt] = *(const v8s*)(&lbp[(wcol + 16 * tt + l16) * BK + sfrag * 8]);
        }
        #pragma unroll
        for (int mt = 0; mt < 4; ++mt)
            #pragma unroll
            for (int nt = 0; nt < 4; ++nt)
                acc[mt][nt] = __builtin_amdgcn_mfma_f32_16x16x32_bf16(
                    af[mt], bfr[nt], acc[mt][nt], 0, 0, 0);
    }

    // ---- e = exp(d * rn_i * rn_j) in place ----
    #pragma unroll
    for (int mt = 0; mt < 4; ++mt) {
        #pragma unroll
        for (int nt = 0; nt < 4; ++nt) {
            float rj = rnB[wcol + 16 * nt + l16];
            #pragma unroll
            for (int r = 0; r < 4; ++r) {
                float ri = rnA[wrow + 16 * mt + quad * 4 + r];
                acc[mt][nt][r] = __expf(acc[mt][nt][r] * ri * rj);
            }
        }
    }

    // ---- row pass: per-wave half-row sums -> LDS ----
    #pragma unroll
    for (int mt = 0; mt < 4; ++mt) {
        #pragma unroll
        for (int r = 0; r < 4; ++r) {
            int gil = wrow + 16 * mt + quad * 4 + r;      // 0..127
            int gi = i0 + gil;
            int partner = gi ^ BHALF;
            float pd = 0.f, pn = 0.f;
            #pragma unroll
            for (int nt = 0; nt < 4; ++nt) {
                int gj = j0 + wcol + 16 * nt + l16;
                float e = acc[mt][nt][r];
                if (gj == partner) cpos[gi] = e * e;
                if (gj != gi && gj != partner) { pd += e; pn += e * e * e; }
            }
            #pragma unroll
            for (int m = 1; m < 16; m <<= 1) {
                pd += __shfl_xor(pd, m);
                pn += __shfl_xor(pn, m);
            }
            if (l16 == 0) { s_dr[gil][wcol >> 6] = pd; s_nr[gil][wcol >> 6] = pn; }
        }
    }

    // ---- col pass (off-diagonal): per-wave half-col sums -> LDS ----
    if (!diag) {
        #pragma unroll
        for (int nt = 0; nt < 4; ++nt) {
            int gjl = wcol + 16 * nt + l16;               // 0..127
            int gj = j0 + gjl;
            int pj = gj ^ BHALF;
            float cd = 0.f, cn = 0.f;
            #pragma unroll
            for (int mt = 0; mt < 4; ++mt) {
                #pragma unroll
                for (int r = 0; r < 4; ++r) {
                    int gi = i0 + wrow + 16 * mt + quad * 4 + r;
                    float e = acc[mt][nt][r];
                    if (gi == pj) cpos[gj] = e * e;
                    else { cd += e; cn += e * e * e; }
                }
            }
            cd += __shfl_xor(cd, 16); cn += __shfl_xor(cn, 16);
            cd += __shfl_xor(cd, 32); cn += __shfl_xor(cn, 32);
            if (quad == 0) { s_dc[gjl][wrow >> 6] = cd; s_nc[gjl][wrow >> 6] = cn; }
        }
    }

    __syncthreads();
    // ---- combine wave halves, single coalesced store per slot ----
    if (tid < BM) {
        pden[(size_t)bj * NROWS + i0 + tid] = s_dr[tid][0] + s_dr[tid][1];
        pnum[(size_t)bj * NROWS + i0 + tid] = s_nr[tid][0] + s_nr[tid][1];
        if (!diag) {
            pden[(size_t)bi * NROWS + j0 + tid] = s_dc[tid][0] + s_dc[tid][1];
            pnum[(size_t)bi * NROWS + j0 + tid] = s_nc[tid][0] + s_nc[tid][1];
        }
    }
}

// -------- Kernel 3a: fold 64 partials per row -> per-block loss partial --------
__global__ __launch_bounds__(256) void finalizeA_kernel(
    const float* __restrict__ pden, const float* __restrict__ pnum,
    const float* __restrict__ cpos, float* __restrict__ bpart)
{
    int i = blockIdx.x * 256 + threadIdx.x;    // row, RBLK*256 == NROWS
    float den = 0.f, num = 0.f;
    #pragma unroll 8
    for (int x = 0; x < NTIL; ++x) {
        den += pden[(size_t)x * NROWS + i];
        num += pnum[(size_t)x * NROWS + i];
    }
    float s = logf(1.0f + KNEG * (num / den) / cpos[i]);
    for (int m = 32; m; m >>= 1) s += __shfl_xor(s, m);
    __shared__ float wsum[4];
    if ((threadIdx.x & 63) == 0) wsum[threadIdx.x >> 6] = s;
    __syncthreads();
    if (threadIdx.x == 0)
        bpart[blockIdx.x] = wsum[0] + wsum[1] + wsum[2] + wsum[3];
}

// -------- Kernel 3b: final scalar --------
__global__ void finalizeB_kernel(const float* __restrict__ bpart, float* __restrict__ out)
{
    int lane = threadIdx.x;
    float s = (lane < RBLK) ? bpart[lane] : 0.f;
    for (int m = 32; m; m >>= 1) s += __shfl_xor(s, m);
    if (lane == 0) out[0] = s / (float)NROWS;
}

extern "C" void kernel_launch(void* const* d_in, const int* in_sizes, int n_in,
                              void* d_out, int out_size, void* d_ws, size_t ws_size,
                              hipStream_t stream)
{
    const void* o1 = d_in[1];
    const void* o2 = d_in[2];

    // ws: pden 2MB | pnum 2MB | rn 32KB | cpos 32KB | bpart | flag  (~4.13 MB)
    float* pden = (float*)d_ws;
    float* pnum = pden + (size_t)NTIL * NROWS;
    float* rn   = pnum + (size_t)NTIL * NROWS;
    float* cpos = rn + NROWS;
    float* bpart= cpos + NROWS;
    int*   flag = (int*)(bpart + RBLK);

    dtype_probe<<<1, 64, 0, stream>>>((const uint32_t*)o1, flag);
    rownorm_kernel<<<NROWS / 4, 256, 0, stream>>>(o1, o2, flag, rn);
    SupCon_hcl_49323404427556_kernel<<<TBLK, 256, 0, stream>>>(o1, o2, flag, rn, pden, pnum, cpos);
    finalizeA_kernel<<<RBLK, 256, 0, stream>>>(pden, pnum, cpos, bpart);
    finalizeB_kernel<<<1, 64, 0, stream>>>(bpart, (float*)d_out);
}